// Round 1
// baseline (347.148 us; speedup 1.0000x reference)
//
#include <hip/hip_runtime.h>
#include <hip/hip_bf16.h>

typedef __attribute__((ext_vector_type(8))) short short8;
typedef __attribute__((ext_vector_type(4))) float f32x4;

#define MFMA16(a,b,c) __builtin_amdgcn_mfma_f32_16x16x32_bf16((a),(b),(c),0,0,0)

static __device__ __forceinline__ unsigned short f2b(float f){
  __hip_bfloat16 h = __float2bfloat16(f);
  return __builtin_bit_cast(unsigned short, h);
}

// ---------------- elementwise f32 -> bf16 ----------------
__global__ __launch_bounds__(256) void k_convert_x(const float* __restrict__ x,
                                                   unsigned short* __restrict__ xb, int n){
  int i = (blockIdx.x*256 + threadIdx.x)*8;
  if (i >= n) return;
  float4 a = *(const float4*)(x+i);
  float4 b = *(const float4*)(x+i+4);
  short8 v;
  v[0]=f2b(a.x); v[1]=f2b(a.y); v[2]=f2b(a.z); v[3]=f2b(a.w);
  v[4]=f2b(b.x); v[5]=f2b(b.y); v[6]=f2b(b.z); v[7]=f2b(b.w);
  *(short8*)(xb+i) = v;
}

// ---------------- transpose + convert: in f32 [R][C] -> out bf16 [C][R] ----------------
__global__ void k_transpose_convert(const float* __restrict__ in,
                                    unsigned short* __restrict__ out, int R, int C){
  __shared__ float tile[32][33];
  int c0 = blockIdx.x*32, r0 = blockIdx.y*32;
  int tx = threadIdx.x, ty = threadIdx.y;
  #pragma unroll
  for (int i=0;i<4;i++) tile[ty*4+i][tx] = in[(size_t)(r0+ty*4+i)*C + c0+tx];
  __syncthreads();
  #pragma unroll
  for (int i=0;i<4;i++) out[(size_t)(c0+ty*4+i)*R + r0+tx] = f2b(tile[tx][ty*4+i]);
}

// ---------------- bf16 GEMM: C[M][N] = A[M][K] * BT[N][K]^T, f32 out ----------------
__global__ __launch_bounds__(256,2) void k_gemm_bf16(const unsigned short* __restrict__ A,
    const unsigned short* __restrict__ BT, float* __restrict__ C, int M, int N, int K){
  __shared__ unsigned short As[128*64];
  __shared__ unsigned short Bs[128*64];
  int bm = blockIdx.y*128, bn = blockIdx.x*128;
  int tid = threadIdx.x;
  int wave = tid>>6, lane = tid&63;
  int wr = (wave>>1)*64, wc = (wave&1)*64;
  int r = lane&15, g = lane>>4;
  f32x4 acc[4][4];
  #pragma unroll
  for (int i=0;i<4;i++)
    #pragma unroll
    for (int j=0;j<4;j++){ acc[i][j][0]=0.f; acc[i][j][1]=0.f; acc[i][j][2]=0.f; acc[i][j][3]=0.f; }
  for (int k0=0;k0<K;k0+=64){
    #pragma unroll
    for (int c=0;c<4;c++){
      int id = c*256 + tid;
      int row = id>>3, kc = (id&7)*8;
      *(short8*)&As[row*64+kc] = *(const short8*)&A[(size_t)(bm+row)*K + k0+kc];
      *(short8*)&Bs[row*64+kc] = *(const short8*)&BT[(size_t)(bn+row)*K + k0+kc];
    }
    __syncthreads();
    #pragma unroll
    for (int kk=0;kk<2;kk++){
      short8 af[4], bfr[4];
      #pragma unroll
      for (int i=0;i<4;i++) af[i] = *(const short8*)&As[(wr+i*16+r)*64 + kk*32 + g*8];
      #pragma unroll
      for (int j=0;j<4;j++) bfr[j] = *(const short8*)&Bs[(wc+j*16+r)*64 + kk*32 + g*8];
      #pragma unroll
      for (int i=0;i<4;i++)
        #pragma unroll
        for (int j=0;j<4;j++)
          acc[i][j] = MFMA16(af[i], bfr[j], acc[i][j]);
    }
    __syncthreads();
  }
  #pragma unroll
  for (int i=0;i<4;i++)
    #pragma unroll
    for (int j=0;j<4;j++)
      #pragma unroll
      for (int rr=0;rr<4;rr++)
        C[(size_t)(bm+wr+i*16+4*g+rr)*N + bn+wc+j*16+r] = acc[i][j][rr];
}

// ---------------- RoPE + head split; Q scaled by log2(e)/sqrt(128) ----------------
__global__ __launch_bounds__(256) void k_rope_split(const float* __restrict__ qkv,
    const float* __restrict__ fc, unsigned short* __restrict__ qb,
    unsigned short* __restrict__ kb, unsigned short* __restrict__ vb){
  int row = blockIdx.x;              // b*2048 + t
  int t = row & 2047, b = row >> 11;
  int tid = threadIdx.x;
  const float* qr = qkv + (size_t)row*3072;
  const float QS = 0.12751743f;      // log2(e)/sqrt(128)
  #pragma unroll
  for (int ii=0; ii<4; ii++){        // 1024 q pairs
    int p = tid + 256*ii;
    int h = p>>6, f = p&63;
    float x0 = qr[h*128 + 2*f], x1 = qr[h*128 + 2*f + 1];
    float cs = fc[t*128 + 2*f], sn = fc[t*128 + 2*f + 1];
    float o0 = (x0*cs - x1*sn)*QS, o1 = (x0*sn + x1*cs)*QS;
    size_t o = ((size_t)(b*16 + h)*2048 + t)*128 + 2*f;
    qb[o] = f2b(o0); qb[o+1] = f2b(o1);
  }
  {                                   // 256 k pairs
    int p = tid; int kh = p>>6, f = p&63;
    float x0 = qr[2048 + kh*128 + 2*f], x1 = qr[2048 + kh*128 + 2*f + 1];
    float cs = fc[t*128 + 2*f], sn = fc[t*128 + 2*f + 1];
    float o0 = x0*cs - x1*sn, o1 = x0*sn + x1*cs;
    size_t o = ((size_t)(b*4 + kh)*2048 + t)*128 + 2*f;
    kb[o] = f2b(o0); kb[o+1] = f2b(o1);
  }
  #pragma unroll
  for (int ii=0; ii<2; ii++){         // 512 v elems
    int e = tid + 256*ii;
    int kh = e>>7, d = e&127;
    size_t o = ((size_t)(b*4 + kh)*2048 + t)*128 + d;
    vb[o] = f2b(qr[2560 + e]);
  }
}

// ---------------- V transpose: [bk][2048][128] -> [bk][128][2048] ----------------
__global__ void k_transpose_v(const unsigned short* __restrict__ v,
                              unsigned short* __restrict__ vt){
  __shared__ unsigned short tile[32][33];
  int bk = blockIdx.z;
  int d0 = blockIdx.x*32, t0 = blockIdx.y*32;
  int tx = threadIdx.x, ty = threadIdx.y;
  const unsigned short* vp = v + (size_t)bk*2048*128;
  unsigned short* vtp = vt + (size_t)bk*128*2048;
  #pragma unroll
  for (int i=0;i<4;i++) tile[ty*4+i][tx] = vp[(t0+ty*4+i)*128 + d0+tx];
  __syncthreads();
  #pragma unroll
  for (int i=0;i<4;i++) vtp[(d0+ty*4+i)*2048 + t0+tx] = tile[tx][ty*4+i];
}

// ---------------- sliding-window flash attention ----------------
// grid (T/64, H, B); 4 waves x 16 q-rows; 64-key tiles; online softmax in exp2 domain.
__global__ __launch_bounds__(256) void k_attn(const unsigned short* __restrict__ q,
    const unsigned short* __restrict__ k, const unsigned short* __restrict__ vt,
    unsigned short* __restrict__ y){
  int qb0 = blockIdx.x*64;
  int h = blockIdx.y, b = blockIdx.z;
  int kvh = h>>2;
  int tid = threadIdx.x, wave = tid>>6, lane = tid&63;
  int w0 = qb0 + wave*16;
  int r = lane&15, g = lane>>4;
  const unsigned short* qh = q + ((size_t)(b*16+h)*2048)*128;
  const unsigned short* kh = k + ((size_t)(b*4+kvh)*2048)*128;
  const unsigned short* vh = vt + ((size_t)(b*4+kvh)*128)*2048;
  __shared__ unsigned short plds[4][16][72];

  short8 qf[4];
  #pragma unroll
  for (int c=0;c<4;c++) qf[c] = *(const short8*)&qh[(w0+r)*128 + c*32 + g*8];

  f32x4 acc[8];
  #pragma unroll
  for (int d=0; d<8; d++){ acc[d][0]=0.f; acc[d][1]=0.f; acc[d][2]=0.f; acc[d][3]=0.f; }
  float m[4]  = {-1e30f,-1e30f,-1e30f,-1e30f};
  float ls[4] = {0.f,0.f,0.f,0.f};

  int lo = w0 - 511; if (lo < 0) lo = 0;
  int kt0 = lo & ~63;
  int ktend = w0 + 15;

  for (int kt = kt0; kt <= ktend; kt += 64){
    f32x4 S[4];
    #pragma unroll
    for (int s=0;s<4;s++){
      f32x4 a; a[0]=0.f; a[1]=0.f; a[2]=0.f; a[3]=0.f;
      const unsigned short* kr = &kh[(size_t)(kt + s*16 + r)*128 + g*8];
      #pragma unroll
      for (int c=0;c<4;c++){
        short8 kf = *(const short8*)&kr[c*32];
        a = MFMA16(qf[c], kf, a);
      }
      S[s] = a;
    }
    #pragma unroll
    for (int rr=0;rr<4;rr++){
      int i = w0 + 4*g + rr;
      float mx = -3e38f;
      #pragma unroll
      for (int s=0;s<4;s++){
        int j = kt + s*16 + r;
        bool valid = (j <= i) && (i - j < 512);
        float sv = valid ? S[s][rr] : -3e38f;
        S[s][rr] = sv;
        mx = fmaxf(mx, sv);
      }
      mx = fmaxf(mx, __shfl_xor(mx, 1));
      mx = fmaxf(mx, __shfl_xor(mx, 2));
      mx = fmaxf(mx, __shfl_xor(mx, 4));
      mx = fmaxf(mx, __shfl_xor(mx, 8));
      float mn = fmaxf(m[rr], mx);
      float al = exp2f(m[rr] - mn);
      m[rr] = mn;
      float ps = 0.f;
      #pragma unroll
      for (int s=0;s<4;s++){
        float p = exp2f(S[s][rr] - mn);
        S[s][rr] = p;
        ps += p;
      }
      ls[rr] = ls[rr]*al + ps;
      #pragma unroll
      for (int d=0;d<8;d++) acc[d][rr] *= al;
    }
    // P (f32 D-layout) -> LDS bf16 -> A-fragment layout
    #pragma unroll
    for (int rr=0;rr<4;rr++)
      #pragma unroll
      for (int s=0;s<4;s++)
        plds[wave][4*g+rr][s*16+r] = f2b(S[s][rr]);
    short8 pf0 = *(const short8*)&plds[wave][r][g*8];
    short8 pf1 = *(const short8*)&plds[wave][r][32 + g*8];
    #pragma unroll
    for (int d=0;d<8;d++){
      const unsigned short* vr = &vh[(size_t)(d*16 + r)*2048 + kt + g*8];
      short8 vf0 = *(const short8*)&vr[0];
      short8 vf1 = *(const short8*)&vr[32];
      acc[d] = MFMA16(pf0, vf0, acc[d]);
      acc[d] = MFMA16(pf1, vf1, acc[d]);
    }
  }
  #pragma unroll
  for (int rr=0;rr<4;rr++){
    float s = ls[rr];
    s += __shfl_xor(s, 1);
    s += __shfl_xor(s, 2);
    s += __shfl_xor(s, 4);
    s += __shfl_xor(s, 8);
    float inv = 1.f/s;
    int i = w0 + 4*g + rr;
    #pragma unroll
    for (int d=0;d<8;d++)
      y[((size_t)(b*2048)+i)*2048 + h*128 + d*16 + r] = f2b(acc[d][rr]*inv);
  }
}

extern "C" void kernel_launch(void* const* d_in, const int* in_sizes, int n_in,
                              void* d_out, int out_size, void* d_ws, size_t ws_size,
                              hipStream_t stream) {
  const float* x      = (const float*)d_in[0];
  const float* w_attn = (const float*)d_in[1];
  const float* w_proj = (const float*)d_in[2];
  const float* fc     = (const float*)d_in[3];
  float* out = (float*)d_out;
  char* ws = (char*)d_ws;
  // workspace layout (bytes)
  unsigned short* xb  = (unsigned short*)(ws);             // 16,777,216  x bf16
  unsigned short* wt  = (unsigned short*)(ws + 16777216);  // 12,582,912  w^T bf16 (reused for w_proj^T)
  float*          qkv = (float*)(ws + 29360128);           // 50,331,648  qkv f32
  unsigned short* yb  = (unsigned short*)(ws + 29360128);  // reuse qkv slot after rope
  unsigned short* qb  = (unsigned short*)(ws + 79691776);  // 16,777,216
  unsigned short* kb  = (unsigned short*)(ws + 96468992);  //  4,194,304
  unsigned short* vb  = (unsigned short*)(ws + 100663296); //  4,194,304
  unsigned short* vtb = (unsigned short*)(ws + 104857600); //  4,194,304

  k_convert_x<<<4096, 256, 0, stream>>>(x, xb, 8388608);
  k_transpose_convert<<<dim3(96,64), dim3(32,8), 0, stream>>>(w_attn, wt, 2048, 3072);
  k_gemm_bf16<<<dim3(24,32), 256, 0, stream>>>(xb, wt, qkv, 4096, 3072, 2048);
  k_rope_split<<<4096, 256, 0, stream>>>(qkv, fc, qb, kb, vb);
  k_transpose_v<<<dim3(4,64,8), dim3(32,8), 0, stream>>>(vb, vtb);
  k_transpose_convert<<<dim3(64,64), dim3(32,8), 0, stream>>>(w_proj, wt, 2048, 2048);
  k_attn<<<dim3(32,16,2), 256, 0, stream>>>(qb, kb, vtb, yb);
  k_gemm_bf16<<<dim3(16,32), 256, 0, stream>>>(yb, wt, out, 4096, 2048, 2048);
}

// Round 2
// 205.617 us; speedup vs baseline: 1.6883x; 1.6883x over previous
//
#include <hip/hip_runtime.h>
#include <hip/hip_bf16.h>

typedef __attribute__((ext_vector_type(8))) short short8;
typedef __attribute__((ext_vector_type(4))) float f32x4;

#define MFMA16(a,b,c) __builtin_amdgcn_mfma_f32_16x16x32_bf16((a),(b),(c),0,0,0)

static __device__ __forceinline__ unsigned short f2b(float f){
  __hip_bfloat16 h = __float2bfloat16(f);
  return __builtin_bit_cast(unsigned short, h);
}

static __device__ __forceinline__ void gld_lds16(const void* g, void* l){
  __builtin_amdgcn_global_load_lds((const __attribute__((address_space(1))) unsigned int*)g,
                                   (__attribute__((address_space(3))) unsigned int*)l, 16, 0, 0);
}

// ---------------- elementwise f32 -> bf16 ----------------
__global__ __launch_bounds__(256) void k_convert_x(const float* __restrict__ x,
                                                   unsigned short* __restrict__ xb, int n){
  int i = (blockIdx.x*256 + threadIdx.x)*8;
  if (i >= n) return;
  float4 a = *(const float4*)(x+i);
  float4 b = *(const float4*)(x+i+4);
  short8 v;
  v[0]=f2b(a.x); v[1]=f2b(a.y); v[2]=f2b(a.z); v[3]=f2b(a.w);
  v[4]=f2b(b.x); v[5]=f2b(b.y); v[6]=f2b(b.z); v[7]=f2b(b.w);
  *(short8*)(xb+i) = v;
}

// ---------------- transpose + convert: in f32 [R][C] -> out bf16 [C][R] ----------------
__global__ void k_transpose_convert(const float* __restrict__ in,
                                    unsigned short* __restrict__ out, int R, int C){
  __shared__ float tile[32][33];
  int c0 = blockIdx.x*32, r0 = blockIdx.y*32;
  int tx = threadIdx.x, ty = threadIdx.y;
  #pragma unroll
  for (int i=0;i<4;i++) tile[ty*4+i][tx] = in[(size_t)(r0+ty*4+i)*C + c0+tx];
  __syncthreads();
  #pragma unroll
  for (int i=0;i<4;i++) out[(size_t)(c0+ty*4+i)*R + r0+tx] = f2b(tile[tx][ty*4+i]);
}

// ---------------- bf16 GEMM: C[M][N] = A[M][K] * BT[N][K]^T, f32 out ----------------
// m97 structure: 128x128 tile, BK=64, global_load_lds width=16 staging, 2 barriers/K-step.
__global__ __launch_bounds__(256,2) void k_gemm_bf16(const unsigned short* __restrict__ A,
    const unsigned short* __restrict__ BT, float* __restrict__ C, int M, int N, int K){
  __shared__ unsigned short As[128*64];
  __shared__ unsigned short Bs[128*64];
  int bm = blockIdx.y*128, bn = blockIdx.x*128;
  int tid = threadIdx.x;
  int wave = tid>>6, lane = tid&63;
  int wr = (wave>>1)*64, wc = (wave&1)*64;
  int r = lane&15, g = lane>>4;
  f32x4 acc[4][4];
  #pragma unroll
  for (int i=0;i<4;i++)
    #pragma unroll
    for (int j=0;j<4;j++){ acc[i][j][0]=0.f; acc[i][j][1]=0.f; acc[i][j][2]=0.f; acc[i][j][3]=0.f; }
  for (int k0=0;k0<K;k0+=64){
    #pragma unroll
    for (int c=0;c<4;c++){
      int id = c*256 + tid;
      int row = id>>3, kc = (id&7)*8;
      gld_lds16(&A[(size_t)(bm+row)*K + k0+kc], &As[row*64+kc]);
      gld_lds16(&BT[(size_t)(bn+row)*K + k0+kc], &Bs[row*64+kc]);
    }
    __syncthreads();
    #pragma unroll
    for (int kk=0;kk<2;kk++){
      short8 af[4], bfr[4];
      #pragma unroll
      for (int i=0;i<4;i++) af[i] = *(const short8*)&As[(wr+i*16+r)*64 + kk*32 + g*8];
      #pragma unroll
      for (int j=0;j<4;j++) bfr[j] = *(const short8*)&Bs[(wc+j*16+r)*64 + kk*32 + g*8];
      #pragma unroll
      for (int i=0;i<4;i++)
        #pragma unroll
        for (int j=0;j<4;j++)
          acc[i][j] = MFMA16(af[i], bfr[j], acc[i][j]);
    }
    __syncthreads();
  }
  #pragma unroll
  for (int i=0;i<4;i++)
    #pragma unroll
    for (int j=0;j<4;j++)
      #pragma unroll
      for (int rr=0;rr<4;rr++)
        C[(size_t)(bm+wr+i*16+4*g+rr)*N + bn+wc+j*16+r] = acc[i][j][rr];
}

// ---------------- RoPE + head split; Q scaled by log2(e)/sqrt(128) ----------------
__global__ __launch_bounds__(256) void k_rope_split(const float* __restrict__ qkv,
    const float* __restrict__ fc, unsigned short* __restrict__ qb,
    unsigned short* __restrict__ kb, unsigned short* __restrict__ vb){
  int row = blockIdx.x;              // b*2048 + t
  int t = row & 2047, b = row >> 11;
  int tid = threadIdx.x;
  const float* qr = qkv + (size_t)row*3072;
  const float QS = 0.12751743f;      // log2(e)/sqrt(128)
  #pragma unroll
  for (int ii=0; ii<4; ii++){        // 1024 q pairs
    int p = tid + 256*ii;
    int h = p>>6, f = p&63;
    float x0 = qr[h*128 + 2*f], x1 = qr[h*128 + 2*f + 1];
    float cs = fc[t*128 + 2*f], sn = fc[t*128 + 2*f + 1];
    float o0 = (x0*cs - x1*sn)*QS, o1 = (x0*sn + x1*cs)*QS;
    size_t o = ((size_t)(b*16 + h)*2048 + t)*128 + 2*f;
    qb[o] = f2b(o0); qb[o+1] = f2b(o1);
  }
  {                                   // 256 k pairs
    int p = tid; int kh = p>>6, f = p&63;
    float x0 = qr[2048 + kh*128 + 2*f], x1 = qr[2048 + kh*128 + 2*f + 1];
    float cs = fc[t*128 + 2*f], sn = fc[t*128 + 2*f + 1];
    float o0 = x0*cs - x1*sn, o1 = x0*sn + x1*cs;
    size_t o = ((size_t)(b*4 + kh)*2048 + t)*128 + 2*f;
    kb[o] = f2b(o0); kb[o+1] = f2b(o1);
  }
  #pragma unroll
  for (int ii=0; ii<2; ii++){         // 512 v elems
    int e = tid + 256*ii;
    int kh = e>>7, d = e&127;
    size_t o = ((size_t)(b*4 + kh)*2048 + t)*128 + d;
    vb[o] = f2b(qr[2560 + e]);
  }
}

// ---------------- V transpose: [bk][2048][128] -> [bk][128][2048] ----------------
__global__ void k_transpose_v(const unsigned short* __restrict__ v,
                              unsigned short* __restrict__ vt){
  __shared__ unsigned short tile[32][33];
  int bk = blockIdx.z;
  int d0 = blockIdx.x*32, t0 = blockIdx.y*32;
  int tx = threadIdx.x, ty = threadIdx.y;
  const unsigned short* vp = v + (size_t)bk*2048*128;
  unsigned short* vtp = vt + (size_t)bk*128*2048;
  #pragma unroll
  for (int i=0;i<4;i++) tile[ty*4+i][tx] = vp[(t0+ty*4+i)*128 + d0+tx];
  __syncthreads();
  #pragma unroll
  for (int i=0;i<4;i++) vtp[(d0+ty*4+i)*2048 + t0+tx] = tile[tx][ty*4+i];
}

// ---------------- sliding-window flash attention, LDS-staged K/V ----------------
// grid (T/64, H, B); 4 waves x 16 q-rows. K/V tiles double-buffered in LDS via
// global_load_lds; XOR-swizzled (linear dest + pre-swizzled source + swizzled read).
__global__ __launch_bounds__(256,2) void k_attn(const unsigned short* __restrict__ q,
    const unsigned short* __restrict__ k, const unsigned short* __restrict__ vt,
    unsigned short* __restrict__ y){
  int qb0 = blockIdx.x*64;
  int h = blockIdx.y, b = blockIdx.z;
  int kvh = h>>2;
  int tid = threadIdx.x, wave = tid>>6, lane = tid&63;
  int w0 = qb0 + wave*16;
  int r = lane&15, g = lane>>4;
  const unsigned short* qh = q + ((size_t)(b*16+h)*2048)*128;
  const unsigned short* kh = k + ((size_t)(b*4+kvh)*2048)*128;
  const unsigned short* vh = vt + ((size_t)(b*4+kvh)*128)*2048;

  __shared__ unsigned short Ks[2][64*128];   // [key][d], swizzled
  __shared__ unsigned short Vs[2][128*64];   // [d][key], swizzled
  __shared__ unsigned short plds[4][16][72];

  short8 qf[4];
  #pragma unroll
  for (int c=0;c<4;c++) qf[c] = *(const short8*)&qh[(w0+r)*128 + c*32 + g*8];

  f32x4 acc[8];
  #pragma unroll
  for (int d=0; d<8; d++){ acc[d][0]=0.f; acc[d][1]=0.f; acc[d][2]=0.f; acc[d][3]=0.f; }
  float m[4]  = {-1e30f,-1e30f,-1e30f,-1e30f};
  float ls[4] = {0.f,0.f,0.f,0.f};

  int lo = qb0 - 511; if (lo < 0) lo = 0;
  int t0 = lo & ~63;
  int nt = ((qb0 + 63) - t0)/64 + 1;
  int sw = (r&7)<<4;                 // per-lane read swizzle (row&7 == r&7)

  // STAGE: K tile 16KB (64 rows x 256B) + V tile 16KB (128 rows x 128B)
  #define STAGE(bb, kt)                                                          \
    { _Pragma("unroll")                                                          \
      for (int p=0;p<4;p++){                                                     \
        int c = p*256 + tid;                                                     \
        int row = c>>4, col = (c&15)*16;                                         \
        gld_lds16((const char*)kh + (size_t)((kt)+row)*256 + (col ^ ((row&7)<<4)),\
                  (char*)&Ks[bb][0] + c*16);                                     \
      }                                                                          \
      _Pragma("unroll")                                                          \
      for (int p=0;p<4;p++){                                                     \
        int c = p*256 + tid;                                                     \
        int row = c>>3, col = (c&7)*16;                                          \
        gld_lds16((const char*)vh + (size_t)row*4096 + (size_t)(kt)*2 + (col ^ ((row&7)<<4)),\
                  (char*)&Vs[bb][0] + c*16);                                     \
      }                                                                          \
    }

  STAGE(0, t0);
  __syncthreads();
  int cur = 0;

  for (int it=0; it<nt; it++){
    int kt = t0 + it*64;
    if (it+1 < nt) STAGE(cur^1, t0 + (it+1)*64);

    bool use = (kt <= w0+15) && (kt+63 >= w0-511);
    if (use){
      f32x4 S[4];
      #pragma unroll
      for (int s=0;s<4;s++){
        f32x4 a; a[0]=0.f; a[1]=0.f; a[2]=0.f; a[3]=0.f;
        const char* kr = (const char*)&Ks[cur][0] + (s*16+r)*256;
        #pragma unroll
        for (int c=0;c<4;c++){
          short8 kf = *(const short8*)(kr + ((c*64 + g*16) ^ sw));
          a = MFMA16(qf[c], kf, a);
        }
        S[s] = a;
      }
      #pragma unroll
      for (int rr=0;rr<4;rr++){
        int i = w0 + 4*g + rr;
        float mx = -3e38f;
        #pragma unroll
        for (int s=0;s<4;s++){
          int j = kt + s*16 + r;
          bool valid = (j <= i) && (i - j < 512);
          float sv = valid ? S[s][rr] : -3e38f;
          S[s][rr] = sv;
          mx = fmaxf(mx, sv);
        }
        mx = fmaxf(mx, __shfl_xor(mx, 1));
        mx = fmaxf(mx, __shfl_xor(mx, 2));
        mx = fmaxf(mx, __shfl_xor(mx, 4));
        mx = fmaxf(mx, __shfl_xor(mx, 8));
        float mn = fmaxf(m[rr], mx);
        float al = exp2f(m[rr] - mn);
        m[rr] = mn;
        float ps = 0.f;
        #pragma unroll
        for (int s=0;s<4;s++){
          float p = exp2f(S[s][rr] - mn);
          S[s][rr] = p;
          ps += p;
        }
        ls[rr] = ls[rr]*al + ps;
        #pragma unroll
        for (int d=0;d<8;d++) acc[d][rr] *= al;
      }
      // P (f32 D-layout) -> LDS bf16 -> A-fragment layout
      #pragma unroll
      for (int rr=0;rr<4;rr++)
        #pragma unroll
        for (int s=0;s<4;s++)
          plds[wave][4*g+rr][s*16+r] = f2b(S[s][rr]);
      short8 pf0 = *(const short8*)&plds[wave][r][g*8];
      short8 pf1 = *(const short8*)&plds[wave][r][32 + g*8];
      #pragma unroll
      for (int d=0;d<8;d++){
        const char* vr = (const char*)&Vs[cur][0] + (d*16+r)*128;
        short8 vf0 = *(const short8*)(vr + ((g*16) ^ sw));
        short8 vf1 = *(const short8*)(vr + ((64 + g*16) ^ sw));
        acc[d] = MFMA16(pf0, vf0, acc[d]);
        acc[d] = MFMA16(pf1, vf1, acc[d]);
      }
    }
    __syncthreads();
    cur ^= 1;
  }

  #pragma unroll
  for (int rr=0;rr<4;rr++){
    float s = ls[rr];
    s += __shfl_xor(s, 1);
    s += __shfl_xor(s, 2);
    s += __shfl_xor(s, 4);
    s += __shfl_xor(s, 8);
    float inv = 1.f/s;
    int i = w0 + 4*g + rr;
    #pragma unroll
    for (int d=0;d<8;d++)
      y[((size_t)(b*2048)+i)*2048 + h*128 + d*16 + r] = f2b(acc[d][rr]*inv);
  }
}

extern "C" void kernel_launch(void* const* d_in, const int* in_sizes, int n_in,
                              void* d_out, int out_size, void* d_ws, size_t ws_size,
                              hipStream_t stream) {
  const float* x      = (const float*)d_in[0];
  const float* w_attn = (const float*)d_in[1];
  const float* w_proj = (const float*)d_in[2];
  const float* fc     = (const float*)d_in[3];
  float* out = (float*)d_out;
  char* ws = (char*)d_ws;
  unsigned short* xb  = (unsigned short*)(ws);             // 16,777,216  x bf16
  unsigned short* wt  = (unsigned short*)(ws + 16777216);  // 12,582,912  w^T bf16 (reused for w_proj^T)
  float*          qkv = (float*)(ws + 29360128);           // 50,331,648  qkv f32
  unsigned short* yb  = (unsigned short*)(ws + 29360128);  // reuse qkv slot after rope
  unsigned short* qb  = (unsigned short*)(ws + 79691776);  // 16,777,216
  unsigned short* kb  = (unsigned short*)(ws + 96468992);  //  4,194,304
  unsigned short* vb  = (unsigned short*)(ws + 100663296); //  4,194,304
  unsigned short* vtb = (unsigned short*)(ws + 104857600); //  4,194,304

  k_convert_x<<<4096, 256, 0, stream>>>(x, xb, 8388608);
  k_transpose_convert<<<dim3(96,64), dim3(32,8), 0, stream>>>(w_attn, wt, 2048, 3072);
  k_gemm_bf16<<<dim3(24,32), 256, 0, stream>>>(xb, wt, qkv, 4096, 3072, 2048);
  k_rope_split<<<4096, 256, 0, stream>>>(qkv, fc, qb, kb, vb);
  k_transpose_v<<<dim3(4,64,8), dim3(32,8), 0, stream>>>(vb, vtb);
  k_transpose_convert<<<dim3(64,64), dim3(32,8), 0, stream>>>(w_proj, wt, 2048, 2048);
  k_attn<<<dim3(32,16,2), 256, 0, stream>>>(qb, kb, vtb, yb);
  k_gemm_bf16<<<dim3(16,32), 256, 0, stream>>>(yb, wt, out, 4096, 2048, 2048);
}